// Round 4
// baseline (517.660 us; speedup 1.0000x reference)
//
#include <hip/hip_runtime.h>
#include <hip/hip_cooperative_groups.h>

namespace cg = cooperative_groups;

typedef __attribute__((ext_vector_type(8))) __bf16 bf16x8;
typedef __attribute__((ext_vector_type(4))) float f32x4;

union Frag { unsigned short u[8]; bf16x8 b; };

__device__ __forceinline__ unsigned short rne_bf16(float x) {
    unsigned int u = __float_as_uint(x);
    return (unsigned short)((u + 0x7fffu + ((u >> 16) & 1u)) >> 16);
}
__device__ __forceinline__ float bf16_to_f(unsigned short h) {
    return __uint_as_float(((unsigned int)h) << 16);
}

#define MFMA16 __builtin_amdgcn_mfma_f32_16x16x32_bf16
#define SBSH 9
#define SBN 512
#define SBCAP 7168
#define BINCHUNK 4096
#define NWFRAG (3 * 2 * 2 * 4 * 64 * 8)

struct KArgs {
    const float* nf; const int* src; const int* dst; const int* gids;
    const float* Wg; const float* bg; const float* Wr; const float* br;
    const float* Wi; const float* bi; const float* Wo; const float* bo;
    const float* Wp; const float* bp;
    float* out;
    int* gcursor; int* binned; int2* nodeTab;
    unsigned short* nfb; unsigned short* aggb; unsigned short* wfrag;
    float* wfold; float* c0;
    int nBin, nE, nbS, out_size, nNodes, nTiles;
};

// One cooperative kernel, 5 phases, grid.sync() between.
// LDS: union of per-phase needs, 35.0 KB -> 4 blocks/CU.
__global__ __launch_bounds__(256, 4) void fused_kernel(KArgs A) {
    __shared__ union {
        struct { int lhist[256], lbase[256], lofs[256], wsum[4];
                 int sortedV[BINCHUNK], sortedA[BINCHUNK]; } bin;   // 35.0 KB
        struct { int eL[SBCAP], deg[SBN], sc[SBN], wsum[8]; } seg;  // 32.1 KB
        struct { float hs[4][32 * 68]; } m;                          // 34.8 KB
    } U;
    cg::grid_group grid = cg::this_grid();
    const int t = threadIdx.x;
    const int b = blockIdx.x;
    const int G = gridDim.x;
    const int lane = t & 63, wave = t >> 6;

    // ---- phase 0: zero gcursor (replaces hipMemsetAsync) ----
    if (b == 0) A.gcursor[t] = 0;
    grid.sync();

    // ---- phase 1: bin (grid-stride chunks) ----
    for (int c = b; c < A.nBin; c += G) {
        const int e0 = c * BINCHUNK;
        const int e1 = min(e0 + BINCHUNK, A.nE);
        const int cnt = e1 - e0;
        U.bin.lhist[t] = 0;
        __syncthreads();
        int myr[16];
        #pragma unroll
        for (int u = 0; u < 16; ++u) {
            int e = e0 + t + u * 256;
            if (e < e1) myr[u] = atomicAdd(&U.bin.lhist[A.dst[e] >> SBSH], 1);
        }
        __syncthreads();
        int x = U.bin.lhist[t];
        #pragma unroll
        for (int s = 1; s < 64; s <<= 1) {
            int v = __shfl_up(x, s, 64);
            if (lane >= s) x += v;
        }
        if (lane == 63) U.bin.wsum[wave] = x;
        __syncthreads();
        if (t < 4) {
            int y = U.bin.wsum[t];
            #pragma unroll
            for (int s = 1; s < 4; s <<= 1) {
                int v = __shfl_up(y, s, 64);
                if (t >= s) y += v;
            }
            U.bin.wsum[t] = y;
        }
        __syncthreads();
        U.bin.lofs[t] = x + (wave ? U.bin.wsum[wave - 1] : 0);
        if (t < A.nbS) {
            int cc = U.bin.lhist[t];
            U.bin.lbase[t] = cc ? atomicAdd(&A.gcursor[t], cc) : 0;
        }
        __syncthreads();
        #pragma unroll
        for (int u = 0; u < 16; ++u) {
            int e = e0 + t + u * 256;
            if (e < e1) {
                int d = A.dst[e];
                int sb = d >> SBSH;
                int r = myr[u];
                int p = (U.bin.lofs[sb] - U.bin.lhist[sb]) + r;
                U.bin.sortedV[p] = (A.src[e] << SBSH) | (d & (SBN - 1));
                int gp = U.bin.lbase[sb] + r;
                U.bin.sortedA[p] = (gp < SBCAP) ? (sb * SBCAP + gp) : -1;
            }
        }
        __syncthreads();
        for (int i = t; i < cnt; i += 256) {
            int ga = U.bin.sortedA[i];
            if (ga >= 0) A.binned[ga] = U.bin.sortedV[i];
        }
        __syncthreads();
    }
    // ---- phase 1b: prep (all blocks, grid-stride; overlaps bin) ----
    {
        const int tp = b * 256 + t;
        const int nth = G * 256;
        const float4* nf4 = (const float4*)A.nf;
        ushort4* nfb4 = (ushort4*)A.nfb;
        const int nQ = A.nNodes * 16;
        for (int i = tp; i < nQ; i += nth) {
            float4 v = nf4[i];
            ushort4 o;
            o.x = rne_bf16(v.x); o.y = rne_bf16(v.y);
            o.z = rne_bf16(v.z); o.w = rne_bf16(v.w);
            nfb4[i] = o;
        }
        const float* Ws[3] = {A.Wg, A.Wr, A.Wi};
        for (int idx = tp; idx < NWFRAG; idx += nth) {
            int j = idx & 7, ln = (idx >> 3) & 63, nt = (idx >> 9) & 3;
            int kt = (idx >> 11) & 1, part = (idx >> 12) & 1, mat = idx >> 13;
            int k = kt * 32 + ((ln >> 4) << 3) + j;
            int n = nt * 16 + (ln & 15);
            float ww = Ws[mat][k * 64 + n];
            unsigned short hi = rne_bf16(ww);
            A.wfrag[idx] = (part == 0) ? hi : rne_bf16(ww - bf16_to_f(hi));
        }
        if (tp < 64) {
            float s = 0.f;
            for (int j = 0; j < 128; ++j) s += A.Wo[tp * 128 + j] * A.Wp[j];
            A.wfold[tp] = s;
        }
        if (tp == 0) {
            float s = 0.f;
            for (int j = 0; j < 128; ++j) s += A.bo[j] * A.Wp[j];
            A.c0[0] = s;
        }
        if (tp < A.out_size) A.out[tp] = A.bp[0];
    }
    grid.sync();

    // ---- phase 2: segB CSR per super-bucket (grid-stride, 256 thr, pair-scan)
    for (int bk = b; bk < A.nbS; bk += G) {
        const int cnt = min(A.gcursor[bk], SBCAP);
        const int bb = bk * SBCAP;
        U.seg.deg[t] = 0; U.seg.deg[t + 256] = 0;
        __syncthreads();
        int myr[28];
        #pragma unroll
        for (int u = 0; u < 28; ++u) {
            int i = t + u * 256;
            if (i < cnt) {
                int p = A.binned[bb + i];
                U.seg.eL[i] = p;
                myr[u] = atomicAdd(&U.seg.deg[p & (SBN - 1)], 1);
            }
        }
        __syncthreads();
        // pair-scan: thread t owns positions 2t, 2t+1
        int d0 = U.seg.deg[2 * t], d1 = U.seg.deg[2 * t + 1];
        int pp = d0 + d1;
        int x = pp;
        #pragma unroll
        for (int s = 1; s < 64; s <<= 1) {
            int v = __shfl_up(x, s, 64);
            if (lane >= s) x += v;
        }
        if (lane == 63) U.seg.wsum[wave] = x;
        __syncthreads();
        if (t < 4) {
            int y = U.seg.wsum[t];
            #pragma unroll
            for (int s = 1; s < 4; s <<= 1) {
                int v = __shfl_up(y, s, 64);
                if (t >= s) y += v;
            }
            U.seg.wsum[t] = y;
        }
        __syncthreads();
        int incl = x + (wave ? U.seg.wsum[wave - 1] : 0);
        int e0x = incl - pp;
        int e1x = e0x + d0;
        U.seg.sc[2 * t] = e0x; U.seg.sc[2 * t + 1] = e1x;
        int node0 = bk * SBN + 2 * t;
        if (node0 < A.nNodes)     A.nodeTab[node0]     = make_int2(bb + e0x, d0);
        if (node0 + 1 < A.nNodes) A.nodeTab[node0 + 1] = make_int2(bb + e1x, d1);
        __syncthreads();
        #pragma unroll
        for (int u = 0; u < 28; ++u) {
            int i = t + u * 256;
            if (i < cnt) {
                int p = U.seg.eL[i];
                int pos = U.seg.sc[p & (SBN - 1)] + myr[u];
                A.binned[bb + pos] = p >> SBSH;
            }
        }
        __syncthreads();
    }
    grid.sync();

    // ---- phase 3: gather, DUAL-node per wave (16 loads in flight) ----
    {
        const int gw = b * 4 + wave;
        const int nw = G * 4;
        const int half = lane >> 5, cp = lane & 31;
        const ushort2* nfb2 = (const ushort2*)A.nfb;
        auto bigpath = [&](int basex, int dd, float& ax, float& ay) {
            int k = half;
            for (; k + 8 <= dd; k += 8) {
                int s0 = A.binned[basex + k],     s1 = A.binned[basex + k + 2];
                int s2 = A.binned[basex + k + 4], s3 = A.binned[basex + k + 6];
                ushort2 v0 = nfb2[(long)s0 * 32 + cp];
                ushort2 v1 = nfb2[(long)s1 * 32 + cp];
                ushort2 v2 = nfb2[(long)s2 * 32 + cp];
                ushort2 v3 = nfb2[(long)s3 * 32 + cp];
                ax += (bf16_to_f(v0.x) + bf16_to_f(v1.x)) + (bf16_to_f(v2.x) + bf16_to_f(v3.x));
                ay += (bf16_to_f(v0.y) + bf16_to_f(v1.y)) + (bf16_to_f(v2.y) + bf16_to_f(v3.y));
            }
            for (; k < dd; k += 2) {
                int s = A.binned[basex + k];
                ushort2 v = nfb2[(long)s * 32 + cp];
                ax += bf16_to_f(v.x); ay += bf16_to_f(v.y);
            }
        };
        for (int n0 = gw * 2; n0 < A.nNodes; n0 += nw * 2) {
            const int n1 = n0 + 1;
            const bool h1 = (n1 < A.nNodes);
            int2 sd0 = A.nodeTab[n0];
            int2 sd1 = h1 ? A.nodeTab[n1] : make_int2(0, 0);
            const int b0 = sd0.x, d0v = sd0.y, b1 = sd1.x, d1v = sd1.y;
            float ax0 = 0.f, ay0 = 0.f, ax1 = 0.f, ay1 = 0.f;
            if (d0v <= 64 && d1v <= 64) {
                int idx0 = (d0v > 0) ? A.binned[b0 + min(lane, d0v - 1)] : 0;
                int idx1 = (d1v > 0) ? A.binned[b1 + min(lane, d1v - 1)] : 0;
                int dh0 = (d0v > 0) ? ((d0v - half + 1) >> 1) : 0;
                int dh1 = (d1v > 0) ? ((d1v - half + 1) >> 1) : 0;
                int dhm = max(dh0, dh1);
                for (int jb = 0; jb < dhm; jb += 8) {
                    int sA0[8], sA1[8];
                    #pragma unroll
                    for (int u = 0; u < 8; ++u) {
                        int e = 2 * (jb + u) + half;
                        sA0[u] = __shfl(idx0, (e < d0v) ? e : max(d0v - 1, 0), 64);
                        sA1[u] = __shfl(idx1, (e < d1v) ? e : max(d1v - 1, 0), 64);
                    }
                    ushort2 v0[8], v1[8];
                    #pragma unroll
                    for (int u = 0; u < 8; ++u) {
                        v0[u] = nfb2[(long)sA0[u] * 32 + cp];
                        v1[u] = nfb2[(long)sA1[u] * 32 + cp];
                    }
                    #pragma unroll
                    for (int u = 0; u < 8; ++u) {
                        if (jb + u < dh0) { ax0 += bf16_to_f(v0[u].x); ay0 += bf16_to_f(v0[u].y); }
                        if (jb + u < dh1) { ax1 += bf16_to_f(v1[u].x); ay1 += bf16_to_f(v1[u].y); }
                    }
                }
            } else {
                if (d0v > 0) bigpath(b0, d0v, ax0, ay0);
                if (h1 && d1v > 0) bigpath(b1, d1v, ax1, ay1);
            }
            ax0 += __shfl_xor(ax0, 32, 64); ay0 += __shfl_xor(ay0, 32, 64);
            ax1 += __shfl_xor(ax1, 32, 64); ay1 += __shfl_xor(ay1, 32, 64);
            if (half == 0) {
                ushort2 o0; o0.x = rne_bf16(ax0); o0.y = rne_bf16(ay0);
                ((ushort2*)A.aggb)[(long)n0 * 32 + cp] = o0;
                if (h1) {
                    ushort2 o1; o1.x = rne_bf16(ax1); o1.y = rne_bf16(ay1);
                    ((ushort2*)A.aggb)[(long)n1 * 32 + cp] = o1;
                }
            }
        }
    }
    grid.sync();

    // ---- phase 4: MFMA MLP (grid-stride tiles; one wave = 32 nodes) ----
    {
        const int gw = b * 4 + wave;
        const int nw = G * 4;
        float* hs = U.m.hs[wave];
        const int mrow = lane & 15, quad = lane >> 4;
        const unsigned short* wl0 = A.wfrag + lane * 8;
        auto WF = [&](int mat, int part, int kt, int nt) -> bf16x8 {
            return *(const bf16x8*)(wl0 + (size_t)((((mat * 2 + part) * 2 + kt) * 4 + nt) * 64) * 8);
        };
        for (int wid = gw; wid < A.nTiles; wid += nw) {
            const int base = wid * 32;
            Frag aA[2][2], aN[2][2];
            #pragma unroll
            for (int rt = 0; rt < 2; ++rt) {
                const unsigned short* rowA = A.aggb + (long)(base + rt * 16 + mrow) * 64;
                const unsigned short* rowN = A.nfb  + (long)(base + rt * 16 + mrow) * 64;
                #pragma unroll
                for (int kt = 0; kt < 2; ++kt) {
                    aA[rt][kt].b = *(const bf16x8*)(rowA + kt * 32 + quad * 8);
                    aN[rt][kt].b = *(const bf16x8*)(rowN + kt * 32 + quad * 8);
                }
            }
            f32x4 accA[2][4], accR[2][4];
            #pragma unroll
            for (int rt = 0; rt < 2; ++rt)
                #pragma unroll
                for (int nt = 0; nt < 4; ++nt) {
                    accA[rt][nt] = (f32x4){0.f, 0.f, 0.f, 0.f};
                    accR[rt][nt] = (f32x4){0.f, 0.f, 0.f, 0.f};
                }
            #pragma unroll
            for (int nt = 0; nt < 4; ++nt)
                #pragma unroll
                for (int kt = 0; kt < 2; ++kt) {
                    bf16x8 gh = WF(0, 0, kt, nt), gl = WF(0, 1, kt, nt);
                    bf16x8 rh = WF(1, 0, kt, nt), rl = WF(1, 1, kt, nt);
                    #pragma unroll
                    for (int rt = 0; rt < 2; ++rt) {
                        accA[rt][nt] = MFMA16(aA[rt][kt].b, gh, accA[rt][nt], 0, 0, 0);
                        accA[rt][nt] = MFMA16(aA[rt][kt].b, gl, accA[rt][nt], 0, 0, 0);
                        accR[rt][nt] = MFMA16(aN[rt][kt].b, rh, accR[rt][nt], 0, 0, 0);
                        accR[rt][nt] = MFMA16(aN[rt][kt].b, rl, accR[rt][nt], 0, 0, 0);
                    }
                }
            #pragma unroll
            for (int nt = 0; nt < 4; ++nt) {
                float bgv = A.bg[nt * 16 + mrow], brv = A.br[nt * 16 + mrow];
                #pragma unroll
                for (int rt = 0; rt < 2; ++rt)
                    #pragma unroll
                    for (int r = 0; r < 4; ++r) {
                        float h = fmaxf(accA[rt][nt][r] + bgv, 0.f)
                                + fmaxf(accR[rt][nt][r] + brv, 0.f);
                        hs[(rt * 16 + quad * 4 + r) * 68 + nt * 16 + mrow] = h;
                    }
            }
            __builtin_amdgcn_wave_barrier();
            Frag aH[2][2];
            #pragma unroll
            for (int rt = 0; rt < 2; ++rt)
                #pragma unroll
                for (int kt = 0; kt < 2; ++kt) {
                    const float* hp = hs + (rt * 16 + mrow) * 68 + kt * 32 + quad * 8;
                    float4 v0 = *(const float4*)hp;
                    float4 v1 = *(const float4*)(hp + 4);
                    aH[rt][kt].u[0] = rne_bf16(v0.x); aH[rt][kt].u[1] = rne_bf16(v0.y);
                    aH[rt][kt].u[2] = rne_bf16(v0.z); aH[rt][kt].u[3] = rne_bf16(v0.w);
                    aH[rt][kt].u[4] = rne_bf16(v1.x); aH[rt][kt].u[5] = rne_bf16(v1.y);
                    aH[rt][kt].u[6] = rne_bf16(v1.z); aH[rt][kt].u[7] = rne_bf16(v1.w);
                }
            __builtin_amdgcn_wave_barrier();
            f32x4 accH[2][4];
            #pragma unroll
            for (int rt = 0; rt < 2; ++rt)
                #pragma unroll
                for (int nt = 0; nt < 4; ++nt)
                    accH[rt][nt] = (f32x4){0.f, 0.f, 0.f, 0.f};
            #pragma unroll
            for (int nt = 0; nt < 4; ++nt)
                #pragma unroll
                for (int kt = 0; kt < 2; ++kt) {
                    bf16x8 ih = WF(2, 0, kt, nt), il = WF(2, 1, kt, nt);
                    #pragma unroll
                    for (int rt = 0; rt < 2; ++rt) {
                        accH[rt][nt] = MFMA16(aH[rt][kt].b, ih, accH[rt][nt], 0, 0, 0);
                        accH[rt][nt] = MFMA16(aH[rt][kt].b, il, accH[rt][nt], 0, 0, 0);
                    }
                }
            float p[2][4];
            #pragma unroll
            for (int rt = 0; rt < 2; ++rt)
                #pragma unroll
                for (int r = 0; r < 4; ++r) p[rt][r] = 0.f;
            #pragma unroll
            for (int nt = 0; nt < 4; ++nt) {
                float biv = A.bi[nt * 16 + mrow], wfv = A.wfold[nt * 16 + mrow];
                #pragma unroll
                for (int rt = 0; rt < 2; ++rt)
                    #pragma unroll
                    for (int r = 0; r < 4; ++r)
                        p[rt][r] += fmaxf(accH[rt][nt][r] + biv, 0.f) * wfv;
            }
            #pragma unroll
            for (int m = 1; m <= 8; m <<= 1)
                #pragma unroll
                for (int rt = 0; rt < 2; ++rt)
                    #pragma unroll
                    for (int r = 0; r < 4; ++r)
                        p[rt][r] += __shfl_xor(p[rt][r], m, 64);
            const float c0v = A.c0[0];
            #pragma unroll
            for (int rt = 0; rt < 2; ++rt)
                #pragma unroll
                for (int r = 0; r < 4; ++r) p[rt][r] += c0v;
            int gself = A.gids[base + (lane & 31)];
            int g0 = __shfl(gself, 0, 64);
            if (__all(gself == g0)) {
                float pv = 0.f;
                if (mrow == 0) {
                    #pragma unroll
                    for (int rt = 0; rt < 2; ++rt)
                        #pragma unroll
                        for (int r = 0; r < 4; ++r) pv += p[rt][r];
                }
                pv += __shfl_xor(pv, 16, 64);
                pv += __shfl_xor(pv, 32, 64);
                if (lane == 0) atomicAdd(A.out + g0, pv);
            } else if (mrow == 0) {
                #pragma unroll
                for (int rt = 0; rt < 2; ++rt)
                    #pragma unroll
                    for (int r = 0; r < 4; ++r)
                        atomicAdd(A.out + A.gids[base + rt * 16 + quad * 4 + r], p[rt][r]);
            }
        }
    }
}

extern "C" void kernel_launch(void* const* d_in, const int* in_sizes, int n_in,
                              void* d_out, int out_size, void* d_ws, size_t ws_size,
                              hipStream_t stream) {
    const float* node_feats = (const float*)d_in[0];
    const int* src  = (const int*)d_in[2];
    const int* dst  = (const int*)d_in[3];
    const int* gids = (const int*)d_in[4];

    const int nNodes = in_sizes[0] / 64;              // 100000
    const int nE = in_sizes[2];
    const int nbS = (nNodes + SBN - 1) / SBN;         // 196
    const int nBin = (nE + BINCHUNK - 1) / BINCHUNK;  // 293
    const int nTiles = (nNodes + 31) / 32;            // 3125

    // ws: gcursor[256] | binned[nbS*SBCAP] | nodeTab[N] int2 | nfb | aggb | wfrag | wfold | c0
    int* gcursor = (int*)d_ws;
    int* binned  = gcursor + 256;
    int2* nodeTab = (int2*)(binned + (size_t)nbS * SBCAP);
    unsigned short* nfb  = (unsigned short*)(nodeTab + nNodes);
    unsigned short* aggb = nfb + (size_t)nNodes * 64;
    unsigned short* wfrag = aggb + (size_t)nNodes * 64;
    float* wfold = (float*)(wfrag + NWFRAG);
    float* c0 = wfold + 64;

    KArgs A;
    A.nf = node_feats; A.src = src; A.dst = dst; A.gids = gids;
    A.Wg = (const float*)d_in[5];  A.bg = (const float*)d_in[6];
    A.Wr = (const float*)d_in[7];  A.br = (const float*)d_in[8];
    A.Wi = (const float*)d_in[9];  A.bi = (const float*)d_in[10];
    A.Wo = (const float*)d_in[11]; A.bo = (const float*)d_in[12];
    A.Wp = (const float*)d_in[13]; A.bp = (const float*)d_in[14];
    A.out = (float*)d_out;
    A.gcursor = gcursor; A.binned = binned; A.nodeTab = nodeTab;
    A.nfb = nfb; A.aggb = aggb; A.wfrag = wfrag; A.wfold = wfold; A.c0 = c0;
    A.nBin = nBin; A.nE = nE; A.nbS = nbS; A.out_size = out_size;
    A.nNodes = nNodes; A.nTiles = nTiles;

    int maxB = 0;
    hipOccupancyMaxActiveBlocksPerMultiprocessor(&maxB, fused_kernel, 256, 0);
    if (maxB < 1) maxB = 1;
    if (maxB > 8) maxB = 8;
    int G = 256 * maxB;   // 256 CUs on MI355X; cooperative co-residency guaranteed by occupancy query

    void* kp[] = { (void*)&A };
    hipLaunchCooperativeKernel(fused_kernel, dim3(G), dim3(256), kp, 0, stream);
}

// Round 5
// 231.384 us; speedup vs baseline: 2.2372x; 2.2372x over previous
//
#include <hip/hip_runtime.h>

typedef __attribute__((ext_vector_type(8))) __bf16 bf16x8;
typedef __attribute__((ext_vector_type(4))) float f32x4;

union Frag { unsigned short u[8]; bf16x8 b; };

__device__ __forceinline__ unsigned short rne_bf16(float x) {
    unsigned int u = __float_as_uint(x);
    return (unsigned short)((u + 0x7fffu + ((u >> 16) & 1u)) >> 16);
}
__device__ __forceinline__ float bf16_to_f(unsigned short h) {
    return __uint_as_float(((unsigned int)h) << 16);
}

#define MFMA16 __builtin_amdgcn_mfma_f32_16x16x32_bf16
#define SBSH 9
#define SBN 512
#define SBCAP 7168
#define BINCHUNK 4096
#define NWFRAG (3 * 2 * 2 * 4 * 64 * 8)

// ---- bin_kernel: sorted-write binning (LDS counting sort), SBN=512 ---------
__global__ __launch_bounds__(256) void bin_kernel(
    const int* __restrict__ src, const int* __restrict__ dst,
    int* __restrict__ gcursor, int* __restrict__ binned,
    int nE, int nbS) {
    __shared__ int lhist[256], lbase[256], lofs[256];
    __shared__ int wsum[4];
    __shared__ int sortedV[BINCHUNK];      // 16 KB
    __shared__ int sortedA[BINCHUNK];      // 16 KB
    const int t = threadIdx.x;
    const int e0 = blockIdx.x * BINCHUNK;
    const int e1 = min(e0 + BINCHUNK, nE);
    const int cnt = e1 - e0;
    lhist[t] = 0;
    __syncthreads();
    int myr[16];
    #pragma unroll
    for (int u = 0; u < 16; ++u) {
        int e = e0 + t + u * 256;
        if (e < e1) myr[u] = atomicAdd(&lhist[dst[e] >> SBSH], 1);
    }
    __syncthreads();
    const int lane = t & 63, w = t >> 6;
    int x = lhist[t];
    #pragma unroll
    for (int s = 1; s < 64; s <<= 1) {
        int v = __shfl_up(x, s, 64);
        if (lane >= s) x += v;
    }
    if (lane == 63) wsum[w] = x;
    __syncthreads();
    if (t < 4) {
        int y = wsum[t];
        #pragma unroll
        for (int s = 1; s < 4; s <<= 1) {
            int v = __shfl_up(y, s, 64);
            if (t >= s) y += v;
        }
        wsum[t] = y;
    }
    __syncthreads();
    lofs[t] = x + (w ? wsum[w - 1] : 0);
    if (t < nbS) {
        int c = lhist[t];
        lbase[t] = c ? atomicAdd(&gcursor[t], c) : 0;
    }
    __syncthreads();
    #pragma unroll
    for (int u = 0; u < 16; ++u) {
        int e = e0 + t + u * 256;
        if (e < e1) {
            int d = dst[e];
            int sb = d >> SBSH;
            int r = myr[u];
            int p = (lofs[sb] - lhist[sb]) + r;   // excl offset + rank
            sortedV[p] = (src[e] << SBSH) | (d & (SBN - 1));
            int gp = lbase[sb] + r;
            sortedA[p] = (gp < SBCAP) ? (sb * SBCAP + gp) : -1;
        }
    }
    __syncthreads();
    for (int i = t; i < cnt; i += 256) {
        int ga = sortedA[i];
        if (ga >= 0) binned[ga] = sortedV[i];
    }
}

// ---- segB+prep: CSR per super-bucket (blocks < nbS) + prep (blocks >= nbS) -
__global__ __launch_bounds__(1024) void segB_kernel(
    int* __restrict__ binned, const int* __restrict__ gcursor,
    int2* __restrict__ nodeTab,
    const float* __restrict__ nf,
    const float* __restrict__ Wg, const float* __restrict__ Wr,
    const float* __restrict__ Wi, const float* __restrict__ Wo,
    const float* __restrict__ bo, const float* __restrict__ Wp,
    const float* __restrict__ bp,
    unsigned short* __restrict__ nfb, unsigned short* __restrict__ wfrag,
    float* __restrict__ wfold, float* __restrict__ c0, float* __restrict__ out,
    int nbS, int out_size, int nNodes) {
    __shared__ int eL[SBCAP];                // 28 KB edge cache
    __shared__ int deg[SBN], sc[SBN];
    __shared__ int wsum[8];
    const int b = blockIdx.x, t = threadIdx.x;
    if (b < nbS) {
        const int cnt = min(gcursor[b], SBCAP);
        const int bb = b * SBCAP;
        if (t < SBN) deg[t] = 0;
        __syncthreads();
        int myr[7];
        #pragma unroll
        for (int u = 0; u < 7; ++u) {
            int i = t + u * 1024;
            if (i < cnt) {
                int p = binned[bb + i];
                eL[i] = p;
                myr[u] = atomicAdd(&deg[p & (SBN - 1)], 1);
            }
        }
        __syncthreads();
        const int lane = t & 63, w = t >> 6;
        if (t < SBN) {
            int d = deg[t];
            int x = d;
            #pragma unroll
            for (int s = 1; s < 64; s <<= 1) {
                int v = __shfl_up(x, s, 64);
                if (lane >= s) x += v;
            }
            if (lane == 63) wsum[w] = x;
            __syncthreads();
            if (t < 8) {
                int y = wsum[t];
                #pragma unroll
                for (int s = 1; s < 8; s <<= 1) {
                    int v = __shfl_up(y, s, 64);
                    if (t >= s) y += v;
                }
                wsum[t] = y;
            }
            __syncthreads();
            int incl = x + (w ? wsum[w - 1] : 0);
            int excl = incl - d;
            sc[t] = excl;
            int node = b * SBN + t;
            if (node < nNodes) nodeTab[node] = make_int2(bb + excl, d);
        } else {
            __syncthreads();
            __syncthreads();
        }
        __syncthreads();
        #pragma unroll
        for (int u = 0; u < 7; ++u) {
            int i = t + u * 1024;
            if (i < cnt) {
                int p = eL[i];
                int pos = sc[p & (SBN - 1)] + myr[u];
                binned[bb + pos] = p >> SBSH;
            }
        }
        return;
    }
    // ---- prep part (blocks >= nbS) ----
    const int tp = ((int)blockIdx.x - nbS) * 1024 + t;
    const int nth = ((int)gridDim.x - nbS) * 1024;
    const float4* nf4 = (const float4*)nf;
    ushort4* nfb4 = (ushort4*)nfb;
    const int nQ = nNodes * 16;
    for (int i = tp; i < nQ; i += nth) {
        float4 v = nf4[i];
        ushort4 o;
        o.x = rne_bf16(v.x); o.y = rne_bf16(v.y);
        o.z = rne_bf16(v.z); o.w = rne_bf16(v.w);
        nfb4[i] = o;
    }
    const float* Ws[3] = {Wg, Wr, Wi};
    for (int idx = tp; idx < NWFRAG; idx += nth) {
        int j = idx & 7, lane = (idx >> 3) & 63, nt = (idx >> 9) & 3;
        int kt = (idx >> 11) & 1, part = (idx >> 12) & 1, mat = idx >> 13;
        int k = kt * 32 + ((lane >> 4) << 3) + j;
        int n = nt * 16 + (lane & 15);
        float ww = Ws[mat][k * 64 + n];
        unsigned short hi = rne_bf16(ww);
        wfrag[idx] = (part == 0) ? hi : rne_bf16(ww - bf16_to_f(hi));
    }
    if (tp < 64) {
        float s = 0.f;
        for (int j = 0; j < 128; ++j) s += Wo[tp * 128 + j] * Wp[j];
        wfold[tp] = s;
    }
    if (tp == 0) {
        float s = 0.f;
        for (int j = 0; j < 128; ++j) s += bo[j] * Wp[j];
        c0[0] = s;
    }
    if (tp < out_size) out[tp] = bp[0];
}

// ---- fused gather + MFMA MLP: one block (4 waves) per 32-node tile ---------
// Gather: wave w handles 8 nodes (serial depth 8, full-wave channel layout).
// Agg staged in LDS (union'd with hs). Wave 0 then runs the MFMA pipeline.
__global__ __launch_bounds__(256) void gathermlp_kernel(
    const unsigned short* __restrict__ nfb, const int2* __restrict__ nodeTab,
    const int* __restrict__ srcs, const int* __restrict__ gids,
    const unsigned short* __restrict__ wfrag,
    const float* __restrict__ bg, const float* __restrict__ br,
    const float* __restrict__ bi, const float* __restrict__ wfold,
    const float* __restrict__ c0p, float* __restrict__ out,
    int nTiles, int nNodes) {
    __shared__ union {
        unsigned short agg[32][72];   // 4.6 KB (row stride 72 shorts)
        float hs[32][68];             // 8.7 KB
    } U;
    const int wave = threadIdx.x >> 6, lane = threadIdx.x & 63;
    const int wid = blockIdx.x;
    if (wid >= nTiles) return;
    const int base = wid * 32;
    const int half = lane >> 5, cp = lane & 31;
    const ushort2* nfb2 = (const ushort2*)nfb;

    // ---- gather phase: wave w gathers nodes [w*8, w*8+8) of this tile ----
    int sdx = 0, sdy = 0;
    {
        int n = base + wave * 8 + (lane & 7);
        if (lane < 8 && n < nNodes) {
            int2 sd = nodeTab[n];
            sdx = sd.x; sdy = sd.y;
        }
    }
    #pragma unroll 1
    for (int i = 0; i < 8; ++i) {
        const int rbase = __shfl(sdx, i, 64);
        const int d     = __shfl(sdy, i, 64);
        float ax = 0.f, ay = 0.f;
        if (d > 0 && d <= 64) {
            int myidx = srcs[rbase + min(lane, d - 1)];
            int dh = (d - half + 1) >> 1;
            for (int jb = 0; jb < dh; jb += 8) {
                int sA[8];
                #pragma unroll
                for (int u = 0; u < 8; ++u) {
                    int e = 2 * (jb + u) + half;
                    sA[u] = __shfl(myidx, (e < d) ? e : (d - 1), 64);
                }
                ushort2 v[8];
                #pragma unroll
                for (int u = 0; u < 8; ++u)
                    v[u] = nfb2[(long)sA[u] * 32 + cp];
                #pragma unroll
                for (int u = 0; u < 8; ++u)
                    if (jb + u < dh) { ax += bf16_to_f(v[u].x); ay += bf16_to_f(v[u].y); }
            }
        } else if (d > 64) {
            int k = half;
            for (; k + 8 <= d; k += 8) {
                int s0 = srcs[rbase + k],     s1 = srcs[rbase + k + 2];
                int s2 = srcs[rbase + k + 4], s3 = srcs[rbase + k + 6];
                ushort2 v0 = nfb2[(long)s0 * 32 + cp];
                ushort2 v1 = nfb2[(long)s1 * 32 + cp];
                ushort2 v2 = nfb2[(long)s2 * 32 + cp];
                ushort2 v3 = nfb2[(long)s3 * 32 + cp];
                ax += (bf16_to_f(v0.x) + bf16_to_f(v1.x)) + (bf16_to_f(v2.x) + bf16_to_f(v3.x));
                ay += (bf16_to_f(v0.y) + bf16_to_f(v1.y)) + (bf16_to_f(v2.y) + bf16_to_f(v3.y));
            }
            for (; k < d; k += 2) {
                int s = srcs[rbase + k];
                ushort2 v = nfb2[(long)s * 32 + cp];
                ax += bf16_to_f(v.x); ay += bf16_to_f(v.y);
            }
        }
        ax += __shfl_xor(ax, 32, 64);
        ay += __shfl_xor(ay, 32, 64);
        if (half == 0) {
            ushort2 o; o.x = rne_bf16(ax); o.y = rne_bf16(ay);
            *(ushort2*)(&U.agg[wave * 8 + i][2 * cp]) = o;
        }
    }
    __syncthreads();
    if (wave != 0) return;

    // ---- MFMA MLP phase (wave 0; agg A-frags from LDS) ----
    const int mrow = lane & 15, quad = lane >> 4;
    Frag aA[2][2], aN[2][2];
    #pragma unroll
    for (int rt = 0; rt < 2; ++rt) {
        const unsigned short* rowA = &U.agg[rt * 16 + mrow][0];
        const unsigned short* rowN = nfb + (long)(base + rt * 16 + mrow) * 64;
        #pragma unroll
        for (int kt = 0; kt < 2; ++kt) {
            aA[rt][kt].b = *(const bf16x8*)(rowA + kt * 32 + quad * 8);
            aN[rt][kt].b = *(const bf16x8*)(rowN + kt * 32 + quad * 8);
        }
    }
    asm volatile("" ::: "memory");
    const unsigned short* wl0 = wfrag + lane * 8;
    auto WF = [&](int mat, int part, int kt, int nt) -> bf16x8 {
        return *(const bf16x8*)(wl0 + (size_t)((((mat * 2 + part) * 2 + kt) * 4 + nt) * 64) * 8);
    };
    f32x4 accA[2][4], accR[2][4];
    #pragma unroll
    for (int rt = 0; rt < 2; ++rt)
        #pragma unroll
        for (int nt = 0; nt < 4; ++nt) {
            accA[rt][nt] = (f32x4){0.f, 0.f, 0.f, 0.f};
            accR[rt][nt] = (f32x4){0.f, 0.f, 0.f, 0.f};
        }
    #pragma unroll
    for (int nt = 0; nt < 4; ++nt)
        #pragma unroll
        for (int kt = 0; kt < 2; ++kt) {
            bf16x8 gh = WF(0, 0, kt, nt), gl = WF(0, 1, kt, nt);
            bf16x8 rh = WF(1, 0, kt, nt), rl = WF(1, 1, kt, nt);
            #pragma unroll
            for (int rt = 0; rt < 2; ++rt) {
                accA[rt][nt] = MFMA16(aA[rt][kt].b, gh, accA[rt][nt], 0, 0, 0);
                accA[rt][nt] = MFMA16(aA[rt][kt].b, gl, accA[rt][nt], 0, 0, 0);
                accR[rt][nt] = MFMA16(aN[rt][kt].b, rh, accR[rt][nt], 0, 0, 0);
                accR[rt][nt] = MFMA16(aN[rt][kt].b, rl, accR[rt][nt], 0, 0, 0);
            }
        }
    asm volatile("" ::: "memory");
    float* hs = &U.hs[0][0];
    #pragma unroll
    for (int nt = 0; nt < 4; ++nt) {
        float bgv = bg[nt * 16 + mrow], brv = br[nt * 16 + mrow];
        #pragma unroll
        for (int rt = 0; rt < 2; ++rt)
            #pragma unroll
            for (int r = 0; r < 4; ++r) {
                float h = fmaxf(accA[rt][nt][r] + bgv, 0.f)
                        + fmaxf(accR[rt][nt][r] + brv, 0.f);
                hs[(rt * 16 + quad * 4 + r) * 68 + nt * 16 + mrow] = h;
            }
    }
    __builtin_amdgcn_wave_barrier();
    Frag aH[2][2];
    #pragma unroll
    for (int rt = 0; rt < 2; ++rt)
        #pragma unroll
        for (int kt = 0; kt < 2; ++kt) {
            const float* hp = hs + (rt * 16 + mrow) * 68 + kt * 32 + quad * 8;
            float4 v0 = *(const float4*)hp;
            float4 v1 = *(const float4*)(hp + 4);
            aH[rt][kt].u[0] = rne_bf16(v0.x); aH[rt][kt].u[1] = rne_bf16(v0.y);
            aH[rt][kt].u[2] = rne_bf16(v0.z); aH[rt][kt].u[3] = rne_bf16(v0.w);
            aH[rt][kt].u[4] = rne_bf16(v1.x); aH[rt][kt].u[5] = rne_bf16(v1.y);
            aH[rt][kt].u[6] = rne_bf16(v1.z); aH[rt][kt].u[7] = rne_bf16(v1.w);
        }
    f32x4 accH[2][4];
    #pragma unroll
    for (int rt = 0; rt < 2; ++rt)
        #pragma unroll
        for (int nt = 0; nt < 4; ++nt)
            accH[rt][nt] = (f32x4){0.f, 0.f, 0.f, 0.f};
    #pragma unroll
    for (int nt = 0; nt < 4; ++nt)
        #pragma unroll
        for (int kt = 0; kt < 2; ++kt) {
            bf16x8 ih = WF(2, 0, kt, nt), il = WF(2, 1, kt, nt);
            #pragma unroll
            for (int rt = 0; rt < 2; ++rt) {
                accH[rt][nt] = MFMA16(aH[rt][kt].b, ih, accH[rt][nt], 0, 0, 0);
                accH[rt][nt] = MFMA16(aH[rt][kt].b, il, accH[rt][nt], 0, 0, 0);
            }
        }
    float p[2][4];
    #pragma unroll
    for (int rt = 0; rt < 2; ++rt)
        #pragma unroll
        for (int r = 0; r < 4; ++r) p[rt][r] = 0.f;
    #pragma unroll
    for (int nt = 0; nt < 4; ++nt) {
        float biv = bi[nt * 16 + mrow], wfv = wfold[nt * 16 + mrow];
        #pragma unroll
        for (int rt = 0; rt < 2; ++rt)
            #pragma unroll
            for (int r = 0; r < 4; ++r)
                p[rt][r] += fmaxf(accH[rt][nt][r] + biv, 0.f) * wfv;
    }
    #pragma unroll
    for (int m = 1; m <= 8; m <<= 1)
        #pragma unroll
        for (int rt = 0; rt < 2; ++rt)
            #pragma unroll
            for (int r = 0; r < 4; ++r)
                p[rt][r] += __shfl_xor(p[rt][r], m, 64);
    const float c0 = c0p[0];
    #pragma unroll
    for (int rt = 0; rt < 2; ++rt)
        #pragma unroll
        for (int r = 0; r < 4; ++r) p[rt][r] += c0;
    int gself = gids[base + (lane & 31)];
    int g0 = __shfl(gself, 0, 64);
    if (__all(gself == g0)) {
        float pv = 0.f;
        if (mrow == 0) {
            #pragma unroll
            for (int rt = 0; rt < 2; ++rt)
                #pragma unroll
                for (int r = 0; r < 4; ++r) pv += p[rt][r];
        }
        pv += __shfl_xor(pv, 16, 64);
        pv += __shfl_xor(pv, 32, 64);
        if (lane == 0) atomicAdd(out + g0, pv);
    } else if (mrow == 0) {
        #pragma unroll
        for (int rt = 0; rt < 2; ++rt)
            #pragma unroll
            for (int r = 0; r < 4; ++r)
                atomicAdd(out + gids[base + rt * 16 + quad * 4 + r], p[rt][r]);
    }
}

extern "C" void kernel_launch(void* const* d_in, const int* in_sizes, int n_in,
                              void* d_out, int out_size, void* d_ws, size_t ws_size,
                              hipStream_t stream) {
    const float* node_feats = (const float*)d_in[0];
    const int* src  = (const int*)d_in[2];
    const int* dst  = (const int*)d_in[3];
    const int* gids = (const int*)d_in[4];
    const float* Wg = (const float*)d_in[5];
    const float* bg = (const float*)d_in[6];
    const float* Wr = (const float*)d_in[7];
    const float* br = (const float*)d_in[8];
    const float* Wi = (const float*)d_in[9];
    const float* bi = (const float*)d_in[10];
    const float* Wo = (const float*)d_in[11];
    const float* bo = (const float*)d_in[12];
    const float* Wp = (const float*)d_in[13];
    const float* bp = (const float*)d_in[14];
    float* out = (float*)d_out;

    const int nNodes = in_sizes[0] / 64;              // 100000
    const int nE = in_sizes[2];
    const int nbS = (nNodes + SBN - 1) / SBN;         // 196
    const int nBin = (nE + BINCHUNK - 1) / BINCHUNK;  // 293
    const int nTiles = (nNodes + 31) / 32;            // 3125

    // ws: gcursor[256] | binned[nbS*SBCAP] | nodeTab[N] int2 | nfb | aggb(unused) | wfrag | wfold | c0
    int* gcursor = (int*)d_ws;
    int* binned  = gcursor + 256;
    int2* nodeTab = (int2*)(binned + (size_t)nbS * SBCAP);
    unsigned short* nfb  = (unsigned short*)(nodeTab + nNodes);
    unsigned short* aggb = nfb + (size_t)nNodes * 64;
    unsigned short* wfrag = aggb + (size_t)nNodes * 64;
    float* wfold = (float*)(wfrag + NWFRAG);
    float* c0 = wfold + 64;

    hipMemsetAsync(gcursor, 0, 256 * sizeof(int), stream);

    bin_kernel<<<nBin, 256, 0, stream>>>(src, dst, gcursor, binned, nE, nbS);

    segB_kernel<<<nbS + 256, 1024, 0, stream>>>(binned, gcursor, nodeTab,
        node_feats, Wg, Wr, Wi, Wo, bo, Wp, bp,
        nfb, wfrag, wfold, c0, out, nbS, out_size, nNodes);

    gathermlp_kernel<<<nTiles, 256, 0, stream>>>(nfb, nodeTab, binned, gids,
        wfrag, bg, br, bi, wfold, c0, out, nTiles, nNodes);
}